// Round 5
// baseline (267.673 us; speedup 1.0000x reference)
//
#include <hip/hip_runtime.h>
#include <hip/hip_bf16.h>

// Problem constants
#define NEGV  (-1000000.0f)
#define OUT_ELEMS   19267584     // 64*64*49*96 (att follows in d_out)
#define ROWS  200704

// ws layout (bytes):
//  [0)      packed bf16 B-fragments: Wb1 27648 ushorts, Wb2 9216 ushorts
//  [73728)  obuf bf16 [ROWS][96] = 38,535,168 B
#define WB2_USH     27648
#define OBUF_OFF_B  73728

// k12 LDS layout (ushort offsets)
//  pbuf [8][64][72]  36864  (xt [64][104]=6656 overlays; xt dead before pbuf use)
//  kbuf [8][49][40]  15680  (K-dim pad cols 12..31 MUST be zero)
//  qbuf [8][49][40]  15680  (ditto — 0 x NaN = NaN, so BOTH operands' pads are zeroed)
//  vtbuf[8][16][72]   9216  (V^T: [d][r]; pad cols 49..63 MUST be zero)
#define PBUF_OFF   0
#define XT_OFF     0
#define KBUF_OFF   36864
#define QBUF_OFF   52544
#define VTBUF_OFF  68224
#define SMEM_USH   77440

typedef __bf16 bf16x8 __attribute__((ext_vector_type(8)));
typedef float  f32x4  __attribute__((ext_vector_type(4)));

static __device__ __forceinline__ unsigned short f2bf(float a) {
    union { float f; unsigned u; } x; x.f = a;
    return (unsigned short)((x.u + 0x7FFFu + ((x.u >> 16) & 1u)) >> 16);
}
static __device__ __forceinline__ unsigned f2bf_pack(float a, float b) {
    return (unsigned)f2bf(a) | ((unsigned)f2bf(b) << 16);
}
static __device__ __forceinline__ bf16x8 as_bf16x8(uint4 u) {
    union { uint4 u; bf16x8 b; } x; x.u = u; return x.b;
}
static __device__ __forceinline__ bf16x8 lds_b128(const unsigned short* p) {
    return as_bf16x8(*(const uint4*)p);
}

// ---------------- prep: pack weights into MFMA B-fragment layout (bf16) ----------------
__global__ void prep_pack(const float* __restrict__ Wk,
                          const float* __restrict__ Wo,
                          unsigned short* __restrict__ wb) {
    int i = blockIdx.x * 256 + threadIdx.x;   // 0..36863
    if (i < WB2_USH) {
        int j = i & 7, l = (i >> 3) & 63, nk = i >> 9;     // nk = nt*3+ks
        int nt = nk / 3, ks = nk - nt * 3;
        int n = nt * 16 + (l & 15);
        int k = ks * 32 + ((l >> 4) << 3) + j;
        wb[i] = f2bf(Wk[n * 96 + k]);
    } else if (i < 36864) {
        int r = i - WB2_USH;
        int j = r & 7, l = (r >> 3) & 63, nk = r >> 9;
        int nt = nk / 3, ks = nk - nt * 3;
        int n = nt * 16 + (l & 15);
        int k = ks * 32 + ((l >> 4) << 3) + j;
        wb[i] = f2bf(Wo[n * 96 + k]);
    }
}

// ---------------- K12: fused shift-gather + kqv GEMM + MFMA attention ----------------
// One block per b (grid 4096, 512 threads = 8 waves). Wave h = head h in attn phase.
__global__ __launch_bounds__(512) void k12(
        const float* __restrict__ window,
        const float* __restrict__ b_kqv,
        const unsigned short* __restrict__ wb1,
        float* __restrict__ att_out,
        unsigned short* __restrict__ obuf) {
    __shared__ unsigned short smem[SMEM_USH];
    __shared__ int wv2[512];

    const int t = threadIdx.x, b = blockIdx.x;
    const int w = t >> 6, l = t & 63;
    const int lr = l & 15, lg4 = l >> 4;

    // blanket-zero kbuf+qbuf+vtbuf (40576 ushorts = 20288 dwords).
    // Every LDS element that reaches an MFMA operand must be defined:
    // masking the OUTPUT does not sanitize NaN on the K-dimension (0*NaN=NaN).
    {
        unsigned* z = (unsigned*)(smem + KBUF_OFF);
#pragma unroll
        for (int i = 0; i < 40; ++i) {
            int idx = t + i * 512;
            if (idx < 20288) z[idx] = 0;
        }
    }
    // gather + cvt 49 rows x 96 f32 (shifted-window input) -> xt bf16
    const int bimg = b >> 6, n = b & 63;
    unsigned short* xt = smem + XT_OFF;
    for (int idx = t; idx < 1176; idx += 512) {
        int r = idx / 24, c4 = idx % 24;
        int s = n * 49 + r;
        int y = s / 56, x = s - y * 56;
        int ys = y + 53; if (ys >= 56) ys -= 56;
        int xs = x + 53; if (xs >= 56) xs -= 56;
        int sn = (ys / 7) * 8 + (xs / 7);
        int sp = (ys % 7) * 7 + (xs % 7);
        float4 v = *((const float4*)(window + ((size_t)(bimg * 64 + sn) * 49 + sp) * 96) + c4);
        *(uint2*)&xt[r * 104 + c4 * 4] = make_uint2(f2bf_pack(v.x, v.y), f2bf_pack(v.z, v.w));
    }
    // window-id table for head w (faithful mask: m = (b*8+h) % 64); pad lanes -> -1
    {
        int val = -1;
        if (l < 49) {
            int m = ((b << 3) + w) & 63;
            int wi = m >> 3, wj = m & 7;
            int pi = l / 7, pj = l % 7;
            int y = wi * 7 + pi, x = wj * 7 + pj;
            int ys = y + 53; if (ys >= 56) ys -= 56;
            int xs = x + 53; if (xs >= 56) xs -= 56;
            val = (ys / 7) * 8 + (xs / 7);
        }
        wv2[w * 64 + l] = val;
    }
    __syncthreads();

    // ---- kqv GEMM: wave w -> m-tile (w&3), nt range (w>>2)*9 .. +8 ----
    {
        const int mt = w & 3, nh = w >> 2;
        bf16x8 a[3];
#pragma unroll
        for (int ks = 0; ks < 3; ++ks)
            a[ks] = lds_b128(&xt[(mt * 16 + lr) * 104 + ks * 32 + lg4 * 8]);

#pragma unroll
        for (int j = 0; j < 9; ++j) {
            int nt = nh * 9 + j;
            int col = nt * 16 + lr;          // 0..287
            float bias = b_kqv[col];
            f32x4 acc = {bias, bias, bias, bias};
#pragma unroll
            for (int ks = 0; ks < 3; ++ks) {
                bf16x8 bf = as_bf16x8(*(const uint4*)(wb1 + ((size_t)(nt * 3 + ks) * 64 + l) * 8));
                acc = __builtin_amdgcn_mfma_f32_16x16x32_bf16(a[ks], bf, acc, 0, 0, 0);
            }
            int seg = col / 96;              // uniform per nt (boundaries at 96,192)
            int cc = col - seg * 96;
            int h2 = cc / 12, d2 = cc - h2 * 12;
#pragma unroll
            for (int reg = 0; reg < 4; ++reg) {
                int R = mt * 16 + lg4 * 4 + reg;
                if (R < 49) {
                    unsigned short v = f2bf(acc[reg]);
                    if (seg == 0)      smem[KBUF_OFF + (h2 * 49 + R) * 40 + d2] = v;
                    else if (seg == 1) smem[QBUF_OFF + (h2 * 49 + R) * 40 + d2] = v;
                    else               smem[VTBUF_OFF + (h2 * 16 + d2) * 72 + R] = v;
                }
            }
        }
    }
    __syncthreads();

    // ---- attention: wave w = head h, all via MFMA ----
    const int h = w;
    const unsigned short* kb = smem + KBUF_OFF + h * 49 * 40;
    const unsigned short* qb = smem + QBUF_OFF + h * 49 * 40;
    const unsigned short* vb = smem + VTBUF_OFF + h * 16 * 72;
    unsigned short* pb = smem + PBUF_OFF + h * 64 * 72;
    const int* wvh = wv2 + h * 64;

    // S = Q * K^T  (rows/cols >=49 are garbage; neutralized by mask / discarded)
    f32x4 sc[4][4];
    {
        bf16x8 qa[4];
#pragma unroll
        for (int mt = 0; mt < 4; ++mt)
            qa[mt] = lds_b128(&qb[(mt * 16 + lr) * 40 + lg4 * 8]);
#pragma unroll
        for (int nt = 0; nt < 4; ++nt) {
            bf16x8 kf = lds_b128(&kb[(nt * 16 + lr) * 40 + lg4 * 8]);
#pragma unroll
            for (int mt = 0; mt < 4; ++mt) {
                f32x4 zz = {0.f, 0.f, 0.f, 0.f};
                sc[mt][nt] = __builtin_amdgcn_mfma_f32_16x16x32_bf16(qa[mt], kf, zz, 0, 0, 0);
            }
        }
    }

    int wvr[4], wvm[4][4];
#pragma unroll
    for (int nt = 0; nt < 4; ++nt) wvr[nt] = wvh[nt * 16 + lr];
#pragma unroll
    for (int mt = 0; mt < 4; ++mt)
#pragma unroll
        for (int reg = 0; reg < 4; ++reg) wvm[mt][reg] = wvh[mt * 16 + lg4 * 4 + reg];

    const float scale = 0.2886751345948129f;   // 1/sqrt(12)
    float mxv[4][4], sm[4][4];
#pragma unroll
    for (int mt = 0; mt < 4; ++mt)
#pragma unroll
        for (int reg = 0; reg < 4; ++reg) {
            float mx = -3.0e38f;
#pragma unroll
            for (int nt = 0; nt < 4; ++nt) {
                float v = sc[mt][nt][reg] * scale;
                if (wvr[nt] != wvm[mt][reg]) v += NEGV;
                sc[mt][nt][reg] = v;
                mx = fmaxf(mx, v);
            }
            mxv[mt][reg] = mx;
        }
    // 16-lane row butterflies (row lives across lanes differing in bits 0..3)
#pragma unroll
    for (int mt = 0; mt < 4; ++mt)
#pragma unroll
        for (int reg = 0; reg < 4; ++reg) {
            float mx = mxv[mt][reg];
            mx = fmaxf(mx, __shfl_xor(mx, 1));
            mx = fmaxf(mx, __shfl_xor(mx, 2));
            mx = fmaxf(mx, __shfl_xor(mx, 4));
            mx = fmaxf(mx, __shfl_xor(mx, 8));
            mxv[mt][reg] = mx;
        }
#pragma unroll
    for (int mt = 0; mt < 4; ++mt)
#pragma unroll
        for (int reg = 0; reg < 4; ++reg) {
            float s = 0.f;
#pragma unroll
            for (int nt = 0; nt < 4; ++nt) {
                float e = __expf(sc[mt][nt][reg] - mxv[mt][reg]);
                sc[mt][nt][reg] = e;
                s += e;
            }
            sm[mt][reg] = s;
        }
#pragma unroll
    for (int mt = 0; mt < 4; ++mt)
#pragma unroll
        for (int reg = 0; reg < 4; ++reg) {
            float s = sm[mt][reg];
            s += __shfl_xor(s, 1);
            s += __shfl_xor(s, 2);
            s += __shfl_xor(s, 4);
            s += __shfl_xor(s, 8);
            sm[mt][reg] = 1.0f / s;
        }

    // write P: att (f32, masked) + pbuf (bf16, unconditional)
    float* ab = att_out + ((size_t)((b << 3) + h)) * 2401;
#pragma unroll
    for (int mt = 0; mt < 4; ++mt)
#pragma unroll
        for (int reg = 0; reg < 4; ++reg) {
            int m = mt * 16 + lg4 * 4 + reg;
            float inv = sm[mt][reg];
#pragma unroll
            for (int nt = 0; nt < 4; ++nt) {
                int r = nt * 16 + lr;
                float p = sc[mt][nt][reg] * inv;
                pb[m * 72 + r] = f2bf(p);
                if (m < 49 && r < 49) ab[m * 49 + r] = p;
            }
        }

    // O = P * V  (pbuf cols r>=49 are exp(NEG)=0 and vtbuf pads are zeroed)
    f32x4 oc[4];
#pragma unroll
    for (int mt = 0; mt < 4; ++mt) oc[mt] = (f32x4){0.f, 0.f, 0.f, 0.f};
#pragma unroll
    for (int ks = 0; ks < 2; ++ks) {
        bf16x8 vf = lds_b128(&vb[lr * 72 + ks * 32 + lg4 * 8]);
#pragma unroll
        for (int mt = 0; mt < 4; ++mt) {
            bf16x8 pa = lds_b128(&pb[(mt * 16 + lr) * 72 + ks * 32 + lg4 * 8]);
            oc[mt] = __builtin_amdgcn_mfma_f32_16x16x32_bf16(pa, vf, oc[mt], 0, 0, 0);
        }
    }
#pragma unroll
    for (int mt = 0; mt < 4; ++mt)
#pragma unroll
        for (int reg = 0; reg < 4; ++reg) {
            int m = mt * 16 + lg4 * 4 + reg;
            if (m < 49 && lr < 12)
                obuf[((size_t)(b * 49 + m)) * 96 + h * 12 + lr] = f2bf(oc[mt][reg]);
        }
}

// ---------------- K3: inverse-shift gather + output projection (MFMA bf16) ----------------
__global__ __launch_bounds__(256) void k3_proj(
        const unsigned short* __restrict__ obuf,
        const unsigned short* __restrict__ wb2,
        const float* __restrict__ b_out,
        float* __restrict__ out) {
    __shared__ unsigned short xt[64][104];
    __shared__ float ot[64 * 100];
    const int t = threadIdx.x, blk = blockIdx.x;

#pragma unroll
    for (int i = 0; i < 3; ++i) {
        int idx = t + i * 256;
        int r = idx / 12, c = idx % 12;
        int R = blk * 64 + r;
        int bb = R / 3136, s2 = R - bb * 3136;
        int y2 = s2 / 56, x2 = s2 - y2 * 56;
        int ys = y2 + 4; if (ys >= 56) ys -= 56;
        int xs = x2 + 4; if (xs >= 56) xs -= 56;
        int sn = (ys / 7) * 8 + (xs / 7);
        int sp = (ys % 7) * 7 + (xs % 7);
        uint4 v = *((const uint4*)(obuf + ((size_t)(bb * 64 + sn) * 49 + sp) * 96) + c);
        *(uint4*)&xt[r][c * 8] = v;
    }
    __syncthreads();

    const int w = t >> 6, l = t & 63;
    const int lr = l & 15, lg4 = l >> 4;

    bf16x8 a[3];
#pragma unroll
    for (int ks = 0; ks < 3; ++ks)
        a[ks] = as_bf16x8(*(const uint4*)&xt[w * 16 + lr][ks * 32 + lg4 * 8]);

#pragma unroll
    for (int nt = 0; nt < 6; ++nt) {
        float bias = b_out[nt * 16 + lr];
        f32x4 acc = {bias, bias, bias, bias};
#pragma unroll
        for (int ks = 0; ks < 3; ++ks) {
            bf16x8 bf = as_bf16x8(*(const uint4*)(wb2 + (size_t)((nt * 3 + ks) * 64 + l) * 8));
            acc = __builtin_amdgcn_mfma_f32_16x16x32_bf16(a[ks], bf, acc, 0, 0, 0);
        }
        int col = nt * 16 + lr;
#pragma unroll
        for (int reg = 0; reg < 4; ++reg) {
            int row = w * 16 + lg4 * 4 + reg;
            ot[row * 100 + col] = acc[reg];
        }
    }
    __syncthreads();

#pragma unroll
    for (int i = 0; i < 6; ++i) {
        int idx = t + i * 256;
        int r = idx / 24, c = idx % 24;
        float4 v = *(const float4*)&ot[r * 100 + c * 4];
        *(float4*)(out + ((size_t)(blk * 64 + r)) * 96 + c * 4) = v;
    }
}

extern "C" void kernel_launch(void* const* d_in, const int* in_sizes, int n_in,
                              void* d_out, int out_size, void* d_ws, size_t ws_size,
                              hipStream_t stream) {
    const float* window = (const float*)d_in[0];
    const float* W_kqv  = (const float*)d_in[1];
    const float* b_kqv  = (const float*)d_in[2];
    const float* W_out  = (const float*)d_in[3];
    const float* b_out  = (const float*)d_in[4];

    float* out = (float*)d_out;
    float* att = out + OUT_ELEMS;

    unsigned short* wb   = (unsigned short*)d_ws;
    unsigned short* obuf = (unsigned short*)((char*)d_ws + OBUF_OFF_B);

    prep_pack<<<144, 256, 0, stream>>>(W_kqv, W_out, wb);
    k12<<<4096, 512, 0, stream>>>(window, b_kqv, wb, att, obuf);
    k3_proj<<<3136, 256, 0, stream>>>(obuf, wb + WB2_USH, b_out, out);
}